// Round 11
// baseline (222.245 us; speedup 1.0000x reference)
//
#include <hip/hip_runtime.h>
#include <hip/hip_bf16.h>
#include <cstdint>
#include <cstddef>

#define NQ 131072   // queries
#define MS 512      // memory slots
#define DD 256      // feature dim
#define USPLIT 16   // update-kernel per-slot parallel split

typedef _Float16 f16;
typedef _Float16 f16x8 __attribute__((ext_vector_type(8)));
typedef float f32x4 __attribute__((ext_vector_type(4)));

// ---- monotone float <-> uint encoding for atomicMax on f32 ----
__device__ __forceinline__ unsigned enc_f32(float x) {
  unsigned u = __float_as_uint(x);
  return (u & 0x80000000u) ? ~u : (u | 0x80000000u);
}
__device__ __forceinline__ float dec_f32(unsigned u) {
  unsigned b = (u & 0x80000000u) ? (u & 0x7FFFFFFFu) : ~u;
  return __uint_as_float(b);
}

// exact 2-term f16 split of a float4
__device__ __forceinline__ void cvt4(const float4 v, uint2& uhi, uint2& ulo) {
  union U { f16 h[4]; uint2 u; } a, b;
  float x;
  x = v.x; a.h[0] = (f16)x; b.h[0] = (f16)(x - (float)a.h[0]);
  x = v.y; a.h[1] = (f16)x; b.h[1] = (f16)(x - (float)a.h[1]);
  x = v.z; a.h[2] = (f16)x; b.h[2] = (f16)(x - (float)a.h[2]);
  x = v.w; a.h[3] = (f16)x; b.h[3] = (f16)(x - (float)a.h[3]);
  uhi = a.u; ulo = b.u;
}

// Pre-split keys f32 -> f16 hi/lo:
//   byte offset = ((sch*8+kq)*4 + rg)*4096 + slot_in_half*16 + hf*8
__global__ __launch_bounds__(256) void ksplit_kernel(
    const float* __restrict__ keys, f16* __restrict__ kfh, f16* __restrict__ kfl)
{
  const int t = blockIdx.x * 256 + threadIdx.x;    // 0..32767
  const int S = t >> 6, c4 = t & 63;               // slot, float4-col
  const float4 v = *(const float4*)&keys[(size_t)S * DD + c4 * 4];
  const int sch = S >> 8, slot = S & 255;
  const int kq = c4 >> 3, rg = (c4 >> 1) & 3, hf = c4 & 1;
  uint2 uh, ul;
  cvt4(v, uh, ul);
  const size_t off = ((size_t)((sch * 8 + kq) * 4 + rg)) * 4096 + slot * 16 + hf * 8;
  *(uint2*)((char*)kfh + off) = uh;
  *(uint2*)((char*)kfl + off) = ul;
}

// ======================= score kernel =======================
// Block = 128 q x 128 s, 512 threads (8 waves: wq=wid>>2 in {0,1}, ws=wid&3).
// Wave tile 64x32 (acc[4][2] f32x4 = 32 regs). Next-kq REGISTER PREFETCH:
// loads for kq+1 issued after barrier-2, consumed (cvt+LDS write) after the
// NEXT barrier-1 -> latency hides under a full compute phase.
// LDS regions (2080 B = 128*16+32 pad):
//   KH @0, KL @8320, QH @16640, QL @24960 (end 33280)
//   reduction overlay: redRow u64[128][34] @0, redCol f32[128][2] @34816
#define R_KH 0
#define R_KL 8320
#define R_QH 16640
#define R_QL 24960
#define RSTR 2080

__global__ __launch_bounds__(512, 6) void score_mfma_kernel(
    const float* __restrict__ query,
    const f16* __restrict__ kfh, const f16* __restrict__ kfl,
    unsigned long long* __restrict__ rowPacked,
    unsigned* __restrict__ colmax_enc)
{
  __shared__ __align__(16) unsigned char LDS[36864];

  const int sc = blockIdx.x;      // slot quarter (0..3)
  const int qb = blockIdx.y;      // query block (0..1023)
  const int tid = threadIdx.x;
  const int l = tid & 63, wid = tid >> 6;
  const int wq = wid >> 2, ws = wid & 3;
  const int lg = l >> 4, ll = l & 15;
  const int q0 = qb * 128;

  f32x4 acc[4][2];
#pragma unroll
  for (int i = 0; i < 4; ++i)
#pragma unroll
    for (int j = 0; j < 2; ++j) acc[i][j] = (f32x4){0.f, 0.f, 0.f, 0.f};

  // K staging geometry: thread t stages slot kidx of region krg (16 B KH + KL)
  const int krg = tid >> 7, kidx = tid & 127;
  const size_t kbase0 = ((size_t)(((sc >> 1) * 8) * 4 + krg)) * 4096
                        + (sc & 1) * 2048 + kidx * 16;   // kq term added per iter
  // Q staging geometry: 2 float4 per thread
  const int qr0 = tid >> 3, qc0 = tid & 7;           // idx = tid
  const int qr1 = (tid + 512) >> 3;                  // idx = tid + 512 (same c4)
  const int qw0 = (qc0 >> 1) * RSTR + (qc0 & 1) * 8;

  uint4 kh_v, kl_v;
  float4 t4, t5;
  auto loadT = [&](int kq) {
    const size_t koff = kbase0 + (size_t)kq * 16384;   // (+kq*4)*4096
    kh_v = *(const uint4*)((const char*)kfh + koff);
    kl_v = *(const uint4*)((const char*)kfl + koff);
    const int kofs = kq * 32;
    t4 = *(const float4*)&query[(size_t)(q0 + qr0) * DD + kofs + qc0 * 4];
    t5 = *(const float4*)&query[(size_t)(q0 + qr1) * DD + kofs + qc0 * 4];
  };

  loadT(0);   // prologue
#pragma unroll
  for (int kq = 0; kq < 8; ++kq) {
    __syncthreads();   // prior compute done reading LDS
    // ---- consume prefetch: cvt + LDS writes ----
    {
      uint2 qh0, ql0, qh1, ql1;
      cvt4(t4, qh0, ql0);
      cvt4(t5, qh1, ql1);
      *(uint4*)&LDS[R_KH + krg * RSTR + kidx * 16] = kh_v;
      *(uint4*)&LDS[R_KL + krg * RSTR + kidx * 16] = kl_v;
      *(uint2*)&LDS[R_QH + qw0 + qr0 * 16] = qh0;
      *(uint2*)&LDS[R_QL + qw0 + qr0 * 16] = ql0;
      *(uint2*)&LDS[R_QH + qw0 + qr1 * 16] = qh1;
      *(uint2*)&LDS[R_QL + qw0 + qr1 * 16] = ql1;
    }
    __syncthreads();

    // ---- issue next-tile loads; latency hides under compute ----
    if (kq < 7) loadT(kq + 1);

    // ---- compute: B-frags resident (16 regs), A per-i (8 regs) ----
    f16x8 bh[2], bl[2];
#pragma unroll
    for (int j = 0; j < 2; ++j) {
      const int s = ws * 32 + j * 16 + ll;
      bh[j] = *(const f16x8*)&LDS[R_KH + lg * RSTR + s * 16];
      bl[j] = *(const f16x8*)&LDS[R_KL + lg * RSTR + s * 16];
    }
#pragma unroll
    for (int i = 0; i < 4; ++i) {
      const int r = wq * 64 + i * 16 + ll;
      const f16x8 ah = *(const f16x8*)&LDS[R_QH + lg * RSTR + r * 16];
      const f16x8 al = *(const f16x8*)&LDS[R_QL + lg * RSTR + r * 16];
#pragma unroll
      for (int j = 0; j < 2; ++j) {
        f32x4 c = acc[i][j];
        c = __builtin_amdgcn_mfma_f32_16x16x32_f16(ah, bl[j], c, 0, 0, 0);
        c = __builtin_amdgcn_mfma_f32_16x16x32_f16(al, bh[j], c, 0, 0, 0);
        c = __builtin_amdgcn_mfma_f32_16x16x32_f16(ah, bh[j], c, 0, 0, 0);
        acc[i][j] = c;
      }
    }
  }

  // ---- reductions. C layout (verified R3-R10): elem v of acc[i][j]:
  //   row = wq*64 + i*16 + lg*4 + v, col(block-local) = ws*32 + j*16 + ll
  __syncthreads();
  unsigned long long* redRow = (unsigned long long*)(LDS);   // [128][34]
  float* redCol = (float*)(LDS + 34816);                     // [128][2]

#pragma unroll
  for (int i = 0; i < 4; ++i)
#pragma unroll
    for (int v = 0; v < 4; ++v) {
      float bv = acc[i][0][v];
      int bc = ws * 32 + ll;
      {
        const float x = acc[i][1][v];
        const int c = ws * 32 + 16 + ll;
        if (x > bv) { bv = x; bc = c; }
      }
      const int gidx = sc * 128 + bc;
      unsigned long long p =
          ((unsigned long long)enc_f32(bv) << 32) | (unsigned)(~(unsigned)gidx);
      const unsigned long long q = __shfl_xor(p, 1);
      if (q > p) p = q;
      if ((ll & 1) == 0) {
        const int row = wq * 64 + i * 16 + lg * 4 + v;
        redRow[row * 34 + ws * 8 + (ll >> 1)] = p;
      }
    }

#pragma unroll
  for (int j = 0; j < 2; ++j) {
    float m = acc[0][j][0];
#pragma unroll
    for (int i = 0; i < 4; ++i)
#pragma unroll
      for (int v = 0; v < 4; ++v) m = fmaxf(m, acc[i][j][v]);
    m = fmaxf(m, __shfl_xor(m, 16));
    m = fmaxf(m, __shfl_xor(m, 32));
    if (l < 16) redCol[(ws * 32 + j * 16 + l) * 2 + wq] = m;
  }

  __syncthreads();
  if (tid < 128) {
    unsigned long long p = redRow[tid * 34];
#pragma unroll
    for (int w = 1; w < 32; ++w) {
      const unsigned long long q = redRow[tid * 34 + w];
      if (q > p) p = q;
    }
    atomicMax(&rowPacked[(size_t)qb * 128 + tid], p);
    const float v = fmaxf(redCol[tid * 2], redCol[tid * 2 + 1]);
    atomicMax(&colmax_enc[sc * 128 + tid], enc_f32(v));
  }
}

// ---- weights + per-slot counts ----
__global__ void weight2_kernel(const unsigned long long* __restrict__ rowPacked,
                               const unsigned* __restrict__ colmax_enc,
                               float* __restrict__ w, int* __restrict__ assign,
                               int* __restrict__ pos, int* __restrict__ count)
{
  const int i = blockIdx.x * blockDim.x + threadIdx.x;
  if (i >= NQ) return;
  const unsigned long long p = rowPacked[i];
  const int a = (int)(~(unsigned)(p & 0xFFFFFFFFull));
  const float sv = dec_f32((unsigned)(p >> 32));
  const float cm = dec_f32(colmax_enc[a]);
  w[i] = expf(sv - cm);
  assign[i] = a;
  pos[i] = atomicAdd(&count[a], 1);
}

// ======================= fallback path (round-1, verified) =======================
#define BQ 128
#define BM 128
#define DC 32
#define PAD 132

__global__ __launch_bounds__(256) void score_kernel(
    const float* __restrict__ query, const float* __restrict__ keys,
    int* __restrict__ assign_out, float* __restrict__ sval_out,
    unsigned* __restrict__ colmax_enc)
{
  __shared__ float Qs[DC][PAD];
  __shared__ float Ks[DC][PAD];
  __shared__ float redV[BQ * 16];
  __shared__ int   redI[BQ * 16];

  const int tid = threadIdx.x;
  const int ty = tid >> 4;
  const int tx = tid & 15;
  const int q0 = blockIdx.x * BQ;

  float bestV = -3.4e38f;
  int   bestI = 0;

  for (int mc = 0; mc < MS / BM; ++mc) {
    float acc[8][8];
#pragma unroll
    for (int i = 0; i < 8; ++i)
#pragma unroll
      for (int j = 0; j < 8; ++j) acc[i][j] = 0.f;

    for (int dc = 0; dc < DD; dc += DC) {
      __syncthreads();
#pragma unroll
      for (int it = 0; it < 4; ++it) {
        const int r = (tid >> 3) + it * 32;
        const int d = (tid & 7) * 4;
        const float4 qv = *reinterpret_cast<const float4*>(
            &query[(size_t)(q0 + r) * DD + dc + d]);
        Qs[d + 0][r] = qv.x; Qs[d + 1][r] = qv.y;
        Qs[d + 2][r] = qv.z; Qs[d + 3][r] = qv.w;
        const float4 kv = *reinterpret_cast<const float4*>(
            &keys[(size_t)(mc * BM + r) * DD + dc + d]);
        Ks[d + 0][r] = kv.x; Ks[d + 1][r] = kv.y;
        Ks[d + 2][r] = kv.z; Ks[d + 3][r] = kv.w;
      }
      __syncthreads();
#pragma unroll
      for (int d = 0; d < DC; ++d) {
        float a[8], b[8];
        *reinterpret_cast<float4*>(&a[0]) = *reinterpret_cast<const float4*>(&Qs[d][ty * 8]);
        *reinterpret_cast<float4*>(&a[4]) = *reinterpret_cast<const float4*>(&Qs[d][ty * 8 + 4]);
        *reinterpret_cast<float4*>(&b[0]) = *reinterpret_cast<const float4*>(&Ks[d][tx * 8]);
        *reinterpret_cast<float4*>(&b[4]) = *reinterpret_cast<const float4*>(&Ks[d][tx * 8 + 4]);
#pragma unroll
        for (int i = 0; i < 8; ++i)
#pragma unroll
          for (int j = 0; j < 8; ++j)
            acc[i][j] = fmaf(a[i], b[j], acc[i][j]);
      }
    }

    __syncthreads();
#pragma unroll
    for (int i = 0; i < 8; ++i) {
      float v = acc[i][0]; int jj = 0;
#pragma unroll
      for (int j = 1; j < 8; ++j)
        if (acc[i][j] > v) { v = acc[i][j]; jj = j; }
      redV[(ty * 8 + i) * 16 + tx] = v;
      redI[(ty * 8 + i) * 16 + tx] = mc * BM + tx * 8 + jj;
    }
    __syncthreads();
    if (tid < BQ) {
#pragma unroll
      for (int t = 0; t < 16; ++t) {
        float v = redV[tid * 16 + t];
        if (v > bestV) { bestV = v; bestI = redI[tid * 16 + t]; }
      }
    }
    __syncthreads();
#pragma unroll
    for (int j = 0; j < 8; ++j) {
      float v = acc[0][j];
#pragma unroll
      for (int i = 1; i < 8; ++i) v = fmaxf(v, acc[i][j]);
      redV[(tx * 8 + j) * 16 + ty] = v;
    }
    __syncthreads();
    if (tid < BM) {
      float v = redV[tid * 16];
#pragma unroll
      for (int t = 1; t < 16; ++t) v = fmaxf(v, redV[tid * 16 + t]);
      atomicMax(&colmax_enc[mc * BM + tid], enc_f32(v));
    }
  }

  if (tid < BQ) {
    assign_out[q0 + tid] = bestI;
    sval_out[q0 + tid]   = bestV;
  }
}

__global__ void weight_kernel(const float* __restrict__ sval,
                              const int* __restrict__ assign,
                              const unsigned* __restrict__ colmax_enc,
                              float* __restrict__ w,
                              int* __restrict__ pos,
                              int* __restrict__ count)
{
  int i = blockIdx.x * blockDim.x + threadIdx.x;
  if (i >= NQ) return;
  int a = assign[i];
  float cm = dec_f32(colmax_enc[a]);
  w[i] = expf(sval[i] - cm);
  pos[i] = atomicAdd(&count[a], 1);
}

// ======================= shared tail kernels =======================

__global__ void scan_kernel(const int* __restrict__ count, int* __restrict__ offset)
{
  __shared__ int s[MS];
  int t = threadIdx.x;
  int c = count[t];
  s[t] = c;
  __syncthreads();
  for (int off = 1; off < MS; off <<= 1) {
    int v = (t >= off) ? s[t - off] : 0;
    __syncthreads();
    s[t] += v;
    __syncthreads();
  }
  offset[t] = s[t] - c;
}

// CSR fill; also writes CSR-ordered weights so update1 reads are contiguous
__global__ void fill_kernel(const int* __restrict__ assign,
                            const int* __restrict__ pos,
                            const int* __restrict__ offset,
                            const float* __restrict__ w,
                            int* __restrict__ list,
                            float* __restrict__ wsorted)
{
  int i = blockIdx.x * blockDim.x + threadIdx.x;
  if (i >= NQ) return;
  int a = assign[i];
  const int p = offset[a] + pos[i];
  list[p] = i;
  wsorted[p] = w[i];
}

// stage 1: per-(slot, chunk) partial weighted sum
__global__ __launch_bounds__(256) void update1_kernel(
    const float* __restrict__ value, const float* __restrict__ wsorted,
    const int* __restrict__ list, const int* __restrict__ offset,
    const int* __restrict__ count, float* __restrict__ partial)
{
  const int m = blockIdx.x, c = blockIdx.y, d = threadIdx.x;
  const int off = offset[m];
  const int cnt = count[m];
  float acc = 0.f;
  int j = c;
  for (; j + USPLIT < cnt; j += 2 * USPLIT) {
    const int i0 = list[off + j];
    const int i1 = list[off + j + USPLIT];
    const float w0 = wsorted[off + j], w1 = wsorted[off + j + USPLIT];
    const float v0 = value[(size_t)i0 * DD + d];
    const float v1 = value[(size_t)i1 * DD + d];
    acc = fmaf(w0, v0, acc);
    acc = fmaf(w1, v1, acc);
  }
  if (j < cnt) {
    const int i = list[off + j];
    acc = fmaf(wsorted[off + j], value[(size_t)i * DD + d], acc);
  }
  partial[((size_t)m * USPLIT + c) * DD + d] = acc;
}

// stage 2: sum partials + keys, L2-normalize, store
__global__ __launch_bounds__(256) void update2_kernel(
    const float* __restrict__ partial, const float* __restrict__ keys,
    float* __restrict__ out)
{
  const int m = blockIdx.x, d = threadIdx.x;
  float x = keys[(size_t)m * DD + d];
#pragma unroll
  for (int c = 0; c < USPLIT; ++c)
    x += partial[((size_t)m * USPLIT + c) * DD + d];
  float ss = x * x;
#pragma unroll
  for (int o = 1; o < 64; o <<= 1) ss += __shfl_xor(ss, o);
  __shared__ float wsum[4];
  if ((threadIdx.x & 63) == 0) wsum[threadIdx.x >> 6] = ss;
  __syncthreads();
  float tot = wsum[0] + wsum[1] + wsum[2] + wsum[3];
  float den = fmaxf(sqrtf(tot), 1e-12f);
  out[(size_t)m * DD + d] = x / den;
}

// ======================= launcher =======================

extern "C" void kernel_launch(void* const* d_in, const int* in_sizes, int n_in,
                              void* d_out, int out_size, void* d_ws, size_t ws_size,
                              hipStream_t stream)
{
  const float* keys  = (const float*)d_in[0];
  const float* query = (const float*)d_in[1];
  const float* value = (const float*)d_in[2];
  float* out = (float*)d_out;

  char* ws = (char*)d_ws;
  size_t o = 0;
  auto alloc = [&](size_t bytes) -> void* {
    void* p = ws + o;
    o += (bytes + 255) & ~(size_t)255;
    return p;
  };

  f16* kfh = (f16*)alloc((size_t)MS * DD * 2);
  f16* kfl = (f16*)alloc((size_t)MS * DD * 2);
  unsigned long long* rowPacked = (unsigned long long*)alloc((size_t)NQ * 8);
  unsigned* colmax_enc = (unsigned*)alloc(MS * 4);
  int* count  = (int*)alloc(MS * 4);
  int* offset = (int*)alloc(MS * 4);
  int* assign = (int*)alloc((size_t)NQ * 4);
  float* wgt  = (float*)alloc((size_t)NQ * 4);
  int* pos    = (int*)alloc((size_t)NQ * 4);
  int* list   = (int*)alloc((size_t)NQ * 4);
  float* wsorted = (float*)alloc((size_t)NQ * 4);
  float* partial = (float*)alloc((size_t)MS * USPLIT * DD * 4);
  const size_t mfma_need = o;

  if (ws_size >= mfma_need) {
    hipMemsetAsync(rowPacked, 0, (size_t)NQ * 8, stream);
    hipMemsetAsync(colmax_enc, 0, MS * 4, stream);
    hipMemsetAsync(count, 0, MS * 4, stream);

    ksplit_kernel<<<128, 256, 0, stream>>>(keys, kfh, kfl);
    score_mfma_kernel<<<dim3(4, 1024), 512, 0, stream>>>(query, kfh, kfl,
                                                         rowPacked, colmax_enc);
    weight2_kernel<<<NQ / 256, 256, 0, stream>>>(rowPacked, colmax_enc,
                                                 wgt, assign, pos, count);
    scan_kernel<<<1, MS, 0, stream>>>(count, offset);
    fill_kernel<<<NQ / 256, 256, 0, stream>>>(assign, pos, offset, wgt,
                                              list, wsorted);
    update1_kernel<<<dim3(MS, USPLIT), DD, 0, stream>>>(value, wsorted, list,
                                                        offset, count, partial);
    update2_kernel<<<MS, DD, 0, stream>>>(partial, keys, out);
  } else {
    // --- fallback: round-1 verified fp32-VALU path ---
    size_t o2 = 0;
    auto alloc2 = [&](size_t bytes) -> void* {
      void* p = ws + o2;
      o2 += (bytes + 255) & ~(size_t)255;
      return p;
    };
    unsigned* colmax2 = (unsigned*)alloc2(MS * 4);
    int* count2  = (int*)alloc2(MS * 4);
    int* offset2 = (int*)alloc2(MS * 4);
    int* assign2 = (int*)alloc2((size_t)NQ * 4);
    float* sval2 = (float*)alloc2((size_t)NQ * 4);
    float* wgt2  = (float*)alloc2((size_t)NQ * 4);
    int* pos2    = (int*)alloc2((size_t)NQ * 4);
    int* list2   = (int*)alloc2((size_t)NQ * 4);
    float* wsorted2 = (float*)alloc2((size_t)NQ * 4);
    float* partial2 = (float*)alloc2((size_t)MS * USPLIT * DD * 4);

    hipMemsetAsync(colmax2, 0, MS * 4, stream);
    hipMemsetAsync(count2, 0, MS * 4, stream);

    score_kernel<<<NQ / BQ, 256, 0, stream>>>(query, keys, assign2, sval2, colmax2);
    weight_kernel<<<NQ / 256, 256, 0, stream>>>(sval2, assign2, colmax2, wgt2, pos2, count2);
    scan_kernel<<<1, MS, 0, stream>>>(count2, offset2);
    fill_kernel<<<NQ / 256, 256, 0, stream>>>(assign2, pos2, offset2, wgt2,
                                              list2, wsorted2);
    update1_kernel<<<dim3(MS, USPLIT), DD, 0, stream>>>(value, wsorted2, list2,
                                                        offset2, count2, partial2);
    update2_kernel<<<MS, DD, 0, stream>>>(partial2, keys, out);
  }
}

// Round 12
// 180.600 us; speedup vs baseline: 1.2306x; 1.2306x over previous
//
#include <hip/hip_runtime.h>
#include <hip/hip_bf16.h>
#include <cstdint>
#include <cstddef>

#define NQ 131072   // queries
#define MS 512      // memory slots
#define DD 256      // feature dim
#define USPLIT 16   // update-kernel per-slot parallel split
#define WTHR 1e-7f  // weight significance threshold (see R12 analysis)

typedef _Float16 f16;
typedef _Float16 f16x8 __attribute__((ext_vector_type(8)));
typedef float f32x4 __attribute__((ext_vector_type(4)));

// ---- monotone float <-> uint encoding for atomicMax on f32 ----
__device__ __forceinline__ unsigned enc_f32(float x) {
  unsigned u = __float_as_uint(x);
  return (u & 0x80000000u) ? ~u : (u | 0x80000000u);
}
__device__ __forceinline__ float dec_f32(unsigned u) {
  unsigned b = (u & 0x80000000u) ? (u & 0x7FFFFFFFu) : ~u;
  return __uint_as_float(b);
}

// exact 2-term f16 split of a float4
__device__ __forceinline__ void cvt4(const float4 v, uint2& uhi, uint2& ulo) {
  union U { f16 h[4]; uint2 u; } a, b;
  float x;
  x = v.x; a.h[0] = (f16)x; b.h[0] = (f16)(x - (float)a.h[0]);
  x = v.y; a.h[1] = (f16)x; b.h[1] = (f16)(x - (float)a.h[1]);
  x = v.z; a.h[2] = (f16)x; b.h[2] = (f16)(x - (float)a.h[2]);
  x = v.w; a.h[3] = (f16)x; b.h[3] = (f16)(x - (float)a.h[3]);
  uhi = a.u; ulo = b.u;
}

// Pre-split keys f32 -> f16 hi/lo:
//   byte offset = ((sch*8+kq)*4 + rg)*4096 + slot_in_half*16 + hf*8
__global__ __launch_bounds__(256) void ksplit_kernel(
    const float* __restrict__ keys, f16* __restrict__ kfh, f16* __restrict__ kfl)
{
  const int t = blockIdx.x * 256 + threadIdx.x;    // 0..32767
  const int S = t >> 6, c4 = t & 63;               // slot, float4-col
  const float4 v = *(const float4*)&keys[(size_t)S * DD + c4 * 4];
  const int sch = S >> 8, slot = S & 255;
  const int kq = c4 >> 3, rg = (c4 >> 1) & 3, hf = c4 & 1;
  uint2 uh, ul;
  cvt4(v, uh, ul);
  const size_t off = ((size_t)((sch * 8 + kq) * 4 + rg)) * 4096 + slot * 16 + hf * 8;
  *(uint2*)((char*)kfh + off) = uh;
  *(uint2*)((char*)kfl + off) = ul;
}

// ======================= score kernel =======================
// Block = 128 q x 128 s, 512 threads (8 waves: wq=wid>>2 in {0,1}, ws=wid&3).
// Wave tile 64x32 (acc[4][2] f32x4 = 32 regs).
// SINGLE-BARRIER DOUBLE-BUFFER (T3 minimum 2-phase): per kq, issue loads for
// kq+1, compute on buf[kq&1], stage into buf[(kq+1)&1], ONE __syncthreads.
// Stage-writes overlap compute in the same phase (different buffer).
// LDS: 2 x 32768 B buffers, unpadded region stride 2048 (2-way bank alias = free).
//   per buf: KH @0, KL @8192, QH @16384, QL @24576
//   reduction overlay: redRow u64[128][34] @0, redCol f32[128][2] @34816
#define BUFSZ 32768
#define S_KH 0
#define S_KL 8192
#define S_QH 16384
#define S_QL 24576
#define SSTR 2048

__global__ __launch_bounds__(512, 4) void score_mfma_kernel(
    const float* __restrict__ query,
    const f16* __restrict__ kfh, const f16* __restrict__ kfl,
    unsigned long long* __restrict__ rowPacked,
    unsigned* __restrict__ colmax_enc)
{
  __shared__ __align__(16) unsigned char LDS[65536];

  const int sc = blockIdx.x;      // slot quarter (0..3)
  const int qb = blockIdx.y;      // query block (0..1023)
  const int tid = threadIdx.x;
  const int l = tid & 63, wid = tid >> 6;
  const int wq = wid >> 2, ws = wid & 3;
  const int lg = l >> 4, ll = l & 15;
  const int q0 = qb * 128;

  f32x4 acc[4][2];
#pragma unroll
  for (int i = 0; i < 4; ++i)
#pragma unroll
    for (int j = 0; j < 2; ++j) acc[i][j] = (f32x4){0.f, 0.f, 0.f, 0.f};

  // K staging geometry: thread t stages slot kidx of region krg (16 B KH + KL)
  const int krg = tid >> 7, kidx = tid & 127;
  const size_t kbase0 = ((size_t)(((sc >> 1) * 8) * 4 + krg)) * 4096
                        + (sc & 1) * 2048 + kidx * 16;   // kq term added per iter
  // Q staging geometry: 2 float4 per thread
  const int qr0 = tid >> 3, qc0 = tid & 7;
  const int qr1 = qr0 + 64;
  const int qw0 = (qc0 >> 1) * SSTR + (qc0 & 1) * 8;

  uint4 kh_v, kl_v;
  float4 t4, t5;
  auto loadT = [&](int kq) {
    const size_t koff = kbase0 + (size_t)kq * 16384;   // (+kq*4)*4096
    kh_v = *(const uint4*)((const char*)kfh + koff);
    kl_v = *(const uint4*)((const char*)kfl + koff);
    const int kofs = kq * 32;
    t4 = *(const float4*)&query[(size_t)(q0 + qr0) * DD + kofs + qc0 * 4];
    t5 = *(const float4*)&query[(size_t)(q0 + qr1) * DD + kofs + qc0 * 4];
  };
  auto stageT = [&](int b) {
    uint2 qh0, ql0, qh1, ql1;
    cvt4(t4, qh0, ql0);
    cvt4(t5, qh1, ql1);
    const int bb = b * BUFSZ;
    *(uint4*)&LDS[bb + S_KH + krg * SSTR + kidx * 16] = kh_v;
    *(uint4*)&LDS[bb + S_KL + krg * SSTR + kidx * 16] = kl_v;
    *(uint2*)&LDS[bb + S_QH + qw0 + qr0 * 16] = qh0;
    *(uint2*)&LDS[bb + S_QL + qw0 + qr0 * 16] = ql0;
    *(uint2*)&LDS[bb + S_QH + qw0 + qr1 * 16] = qh1;
    *(uint2*)&LDS[bb + S_QL + qw0 + qr1 * 16] = ql1;
  };

  // prologue: stage kq=0 into buf0
  loadT(0);
  stageT(0);
  __syncthreads();

#pragma unroll
  for (int kq = 0; kq < 8; ++kq) {
    const int bb = (kq & 1) * BUFSZ;
    if (kq < 7) loadT(kq + 1);   // in flight across the compute phase

    // ---- compute on buf[kq&1]: B-frags resident, A per-i ----
    f16x8 bh[2], bl[2];
#pragma unroll
    for (int j = 0; j < 2; ++j) {
      const int s = ws * 32 + j * 16 + ll;
      bh[j] = *(const f16x8*)&LDS[bb + S_KH + lg * SSTR + s * 16];
      bl[j] = *(const f16x8*)&LDS[bb + S_KL + lg * SSTR + s * 16];
    }
#pragma unroll
    for (int i = 0; i < 4; ++i) {
      const int r = wq * 64 + i * 16 + ll;
      const f16x8 ah = *(const f16x8*)&LDS[bb + S_QH + lg * SSTR + r * 16];
      const f16x8 al = *(const f16x8*)&LDS[bb + S_QL + lg * SSTR + r * 16];
#pragma unroll
      for (int j = 0; j < 2; ++j) {
        f32x4 c = acc[i][j];
        c = __builtin_amdgcn_mfma_f32_16x16x32_f16(ah, bl[j], c, 0, 0, 0);
        c = __builtin_amdgcn_mfma_f32_16x16x32_f16(al, bh[j], c, 0, 0, 0);
        c = __builtin_amdgcn_mfma_f32_16x16x32_f16(ah, bh[j], c, 0, 0, 0);
        acc[i][j] = c;
      }
    }

    // ---- stage kq+1 into the OTHER buffer (overlaps compute phase) ----
    if (kq < 7) stageT((kq + 1) & 1);
    __syncthreads();   // single barrier per kq
  }

  // ---- reductions. C layout (verified R3-R11): elem v of acc[i][j]:
  //   row = wq*64 + i*16 + lg*4 + v, col(block-local) = ws*32 + j*16 + ll
  unsigned long long* redRow = (unsigned long long*)(LDS);   // [128][34]
  float* redCol = (float*)(LDS + 34816);                     // [128][2]

#pragma unroll
  for (int i = 0; i < 4; ++i)
#pragma unroll
    for (int v = 0; v < 4; ++v) {
      float bv = acc[i][0][v];
      int bc = ws * 32 + ll;
      {
        const float x = acc[i][1][v];
        const int c = ws * 32 + 16 + ll;
        if (x > bv) { bv = x; bc = c; }
      }
      const int gidx = sc * 128 + bc;
      unsigned long long p =
          ((unsigned long long)enc_f32(bv) << 32) | (unsigned)(~(unsigned)gidx);
      const unsigned long long q = __shfl_xor(p, 1);
      if (q > p) p = q;
      if ((ll & 1) == 0) {
        const int row = wq * 64 + i * 16 + lg * 4 + v;
        redRow[row * 34 + ws * 8 + (ll >> 1)] = p;
      }
    }

#pragma unroll
  for (int j = 0; j < 2; ++j) {
    float m = acc[0][j][0];
#pragma unroll
    for (int i = 0; i < 4; ++i)
#pragma unroll
      for (int v = 0; v < 4; ++v) m = fmaxf(m, acc[i][j][v]);
    m = fmaxf(m, __shfl_xor(m, 16));
    m = fmaxf(m, __shfl_xor(m, 32));
    if (l < 16) redCol[(ws * 32 + j * 16 + l) * 2 + wq] = m;
  }

  __syncthreads();
  if (tid < 128) {
    unsigned long long p = redRow[tid * 34];
#pragma unroll
    for (int w = 1; w < 32; ++w) {
      const unsigned long long q = redRow[tid * 34 + w];
      if (q > p) p = q;
    }
    atomicMax(&rowPacked[(size_t)qb * 128 + tid], p);
    const float v = fmaxf(redCol[tid * 2], redCol[tid * 2 + 1]);
    atomicMax(&colmax_enc[sc * 128 + tid], enc_f32(v));
  }
}

// ---- weights + per-slot counts; filter insignificant weights ----
// w = exp(s - colmax) <= 1; dropping w < WTHR perturbs each output component by
// < cnt * WTHR * max|v| ~ 2e-4, far below the 6e-3 tolerance.
__global__ void weight2_kernel(const unsigned long long* __restrict__ rowPacked,
                               const unsigned* __restrict__ colmax_enc,
                               float* __restrict__ w, int* __restrict__ assign,
                               int* __restrict__ pos, int* __restrict__ count)
{
  const int i = blockIdx.x * blockDim.x + threadIdx.x;
  if (i >= NQ) return;
  const unsigned long long p = rowPacked[i];
  const int a = (int)(~(unsigned)(p & 0xFFFFFFFFull));
  const float sv = dec_f32((unsigned)(p >> 32));
  const float cm = dec_f32(colmax_enc[a]);
  const float wv = expf(sv - cm);
  w[i] = wv;
  assign[i] = a;
  pos[i] = (wv >= WTHR) ? atomicAdd(&count[a], 1) : -1;
}

// ======================= fallback path (round-1, verified) =======================
#define BQ 128
#define BM 128
#define DC 32
#define PAD 132

__global__ __launch_bounds__(256) void score_kernel(
    const float* __restrict__ query, const float* __restrict__ keys,
    int* __restrict__ assign_out, float* __restrict__ sval_out,
    unsigned* __restrict__ colmax_enc)
{
  __shared__ float Qs[DC][PAD];
  __shared__ float Ks[DC][PAD];
  __shared__ float redV[BQ * 16];
  __shared__ int   redI[BQ * 16];

  const int tid = threadIdx.x;
  const int ty = tid >> 4;
  const int tx = tid & 15;
  const int q0 = blockIdx.x * BQ;

  float bestV = -3.4e38f;
  int   bestI = 0;

  for (int mc = 0; mc < MS / BM; ++mc) {
    float acc[8][8];
#pragma unroll
    for (int i = 0; i < 8; ++i)
#pragma unroll
      for (int j = 0; j < 8; ++j) acc[i][j] = 0.f;

    for (int dc = 0; dc < DD; dc += DC) {
      __syncthreads();
#pragma unroll
      for (int it = 0; it < 4; ++it) {
        const int r = (tid >> 3) + it * 32;
        const int d = (tid & 7) * 4;
        const float4 qv = *reinterpret_cast<const float4*>(
            &query[(size_t)(q0 + r) * DD + dc + d]);
        Qs[d + 0][r] = qv.x; Qs[d + 1][r] = qv.y;
        Qs[d + 2][r] = qv.z; Qs[d + 3][r] = qv.w;
        const float4 kv = *reinterpret_cast<const float4*>(
            &keys[(size_t)(mc * BM + r) * DD + dc + d]);
        Ks[d + 0][r] = kv.x; Ks[d + 1][r] = kv.y;
        Ks[d + 2][r] = kv.z; Ks[d + 3][r] = kv.w;
      }
      __syncthreads();
#pragma unroll
      for (int d = 0; d < DC; ++d) {
        float a[8], b[8];
        *reinterpret_cast<float4*>(&a[0]) = *reinterpret_cast<const float4*>(&Qs[d][ty * 8]);
        *reinterpret_cast<float4*>(&a[4]) = *reinterpret_cast<const float4*>(&Qs[d][ty * 8 + 4]);
        *reinterpret_cast<float4*>(&b[0]) = *reinterpret_cast<const float4*>(&Ks[d][tx * 8]);
        *reinterpret_cast<float4*>(&b[4]) = *reinterpret_cast<const float4*>(&Ks[d][tx * 8 + 4]);
#pragma unroll
        for (int i = 0; i < 8; ++i)
#pragma unroll
          for (int j = 0; j < 8; ++j)
            acc[i][j] = fmaf(a[i], b[j], acc[i][j]);
      }
    }

    __syncthreads();
#pragma unroll
    for (int i = 0; i < 8; ++i) {
      float v = acc[i][0]; int jj = 0;
#pragma unroll
      for (int j = 1; j < 8; ++j)
        if (acc[i][j] > v) { v = acc[i][j]; jj = j; }
      redV[(ty * 8 + i) * 16 + tx] = v;
      redI[(ty * 8 + i) * 16 + tx] = mc * BM + tx * 8 + jj;
    }
    __syncthreads();
    if (tid < BQ) {
#pragma unroll
      for (int t = 0; t < 16; ++t) {
        float v = redV[tid * 16 + t];
        if (v > bestV) { bestV = v; bestI = redI[tid * 16 + t]; }
      }
    }
    __syncthreads();
#pragma unroll
    for (int j = 0; j < 8; ++j) {
      float v = acc[0][j];
#pragma unroll
      for (int i = 1; i < 8; ++i) v = fmaxf(v, acc[i][j]);
      redV[(tx * 8 + j) * 16 + ty] = v;
    }
    __syncthreads();
    if (tid < BM) {
      float v = redV[tid * 16];
#pragma unroll
      for (int t = 1; t < 16; ++t) v = fmaxf(v, redV[tid * 16 + t]);
      atomicMax(&colmax_enc[mc * BM + tid], enc_f32(v));
    }
  }

  if (tid < BQ) {
    assign_out[q0 + tid] = bestI;
    sval_out[q0 + tid]   = bestV;
  }
}

__global__ void weight_kernel(const float* __restrict__ sval,
                              const int* __restrict__ assign,
                              const unsigned* __restrict__ colmax_enc,
                              float* __restrict__ w,
                              int* __restrict__ pos,
                              int* __restrict__ count)
{
  int i = blockIdx.x * blockDim.x + threadIdx.x;
  if (i >= NQ) return;
  int a = assign[i];
  float cm = dec_f32(colmax_enc[a]);
  const float wv = expf(sval[i] - cm);
  w[i] = wv;
  pos[i] = (wv >= WTHR) ? atomicAdd(&count[a], 1) : -1;
}

// ======================= shared tail kernels =======================

__global__ void scan_kernel(const int* __restrict__ count, int* __restrict__ offset)
{
  __shared__ int s[MS];
  int t = threadIdx.x;
  int c = count[t];
  s[t] = c;
  __syncthreads();
  for (int off = 1; off < MS; off <<= 1) {
    int v = (t >= off) ? s[t - off] : 0;
    __syncthreads();
    s[t] += v;
    __syncthreads();
  }
  offset[t] = s[t] - c;
}

// CSR fill (filtered); also writes CSR-ordered weights
__global__ void fill_kernel(const int* __restrict__ assign,
                            const int* __restrict__ pos,
                            const int* __restrict__ offset,
                            const float* __restrict__ w,
                            int* __restrict__ list,
                            float* __restrict__ wsorted)
{
  int i = blockIdx.x * blockDim.x + threadIdx.x;
  if (i >= NQ) return;
  const int ps = pos[i];
  if (ps < 0) return;                 // filtered: weight below WTHR
  int a = assign[i];
  const int p = offset[a] + ps;
  list[p] = i;
  wsorted[p] = w[i];
}

// stage 1: per-(slot, chunk) partial weighted sum
__global__ __launch_bounds__(256) void update1_kernel(
    const float* __restrict__ value, const float* __restrict__ wsorted,
    const int* __restrict__ list, const int* __restrict__ offset,
    const int* __restrict__ count, float* __restrict__ partial)
{
  const int m = blockIdx.x, c = blockIdx.y, d = threadIdx.x;
  const int off = offset[m];
  const int cnt = count[m];
  float acc = 0.f;
  int j = c;
  for (; j + USPLIT < cnt; j += 2 * USPLIT) {
    const int i0 = list[off + j];
    const int i1 = list[off + j + USPLIT];
    const float w0 = wsorted[off + j], w1 = wsorted[off + j + USPLIT];
    const float v0 = value[(size_t)i0 * DD + d];
    const float v1 = value[(size_t)i1 * DD + d];
    acc = fmaf(w0, v0, acc);
    acc = fmaf(w1, v1, acc);
  }
  if (j < cnt) {
    const int i = list[off + j];
    acc = fmaf(wsorted[off + j], value[(size_t)i * DD + d], acc);
  }
  partial[((size_t)m * USPLIT + c) * DD + d] = acc;
}

// stage 2: sum partials + keys, L2-normalize, store
__global__ __launch_bounds__(256) void update2_kernel(
    const float* __restrict__ partial, const float* __restrict__ keys,
    float* __restrict__ out)
{
  const int m = blockIdx.x, d = threadIdx.x;
  float x = keys[(size_t)m * DD + d];
#pragma unroll
  for (int c = 0; c < USPLIT; ++c)
    x += partial[((size_t)m * USPLIT + c) * DD + d];
  float ss = x * x;
#pragma unroll
  for (int o = 1; o < 64; o <<= 1) ss += __shfl_xor(ss, o);
  __shared__ float wsum[4];
  if ((threadIdx.x & 63) == 0) wsum[threadIdx.x >> 6] = ss;
  __syncthreads();
  float tot = wsum[0] + wsum[1] + wsum[2] + wsum[3];
  float den = fmaxf(sqrtf(tot), 1e-12f);
  out[(size_t)m * DD + d] = x / den;
}

// ======================= launcher =======================

extern "C" void kernel_launch(void* const* d_in, const int* in_sizes, int n_in,
                              void* d_out, int out_size, void* d_ws, size_t ws_size,
                              hipStream_t stream)
{
  const float* keys  = (const float*)d_in[0];
  const float* query = (const float*)d_in[1];
  const float* value = (const float*)d_in[2];
  float* out = (float*)d_out;

  char* ws = (char*)d_ws;
  size_t o = 0;
  auto alloc = [&](size_t bytes) -> void* {
    void* p = ws + o;
    o += (bytes + 255) & ~(size_t)255;
    return p;
  };

  f16* kfh = (f16*)alloc((size_t)MS * DD * 2);
  f16* kfl = (f16*)alloc((size_t)MS * DD * 2);
  unsigned long long* rowPacked = (unsigned long long*)alloc((size_t)NQ * 8);
  unsigned* colmax_enc = (unsigned*)alloc(MS * 4);
  int* count  = (int*)alloc(MS * 4);
  int* offset = (int*)alloc(MS * 4);
  int* assign = (int*)alloc((size_t)NQ * 4);
  float* wgt  = (float*)alloc((size_t)NQ * 4);
  int* pos    = (int*)alloc((size_t)NQ * 4);
  int* list   = (int*)alloc((size_t)NQ * 4);
  float* wsorted = (float*)alloc((size_t)NQ * 4);
  float* partial = (float*)alloc((size_t)MS * USPLIT * DD * 4);
  const size_t mfma_need = o;

  if (ws_size >= mfma_need) {
    hipMemsetAsync(rowPacked, 0, (size_t)NQ * 8, stream);
    hipMemsetAsync(colmax_enc, 0, MS * 4, stream);
    hipMemsetAsync(count, 0, MS * 4, stream);

    ksplit_kernel<<<128, 256, 0, stream>>>(keys, kfh, kfl);
    score_mfma_kernel<<<dim3(4, 1024), 512, 0, stream>>>(query, kfh, kfl,
                                                         rowPacked, colmax_enc);
    weight2_kernel<<<NQ / 256, 256, 0, stream>>>(rowPacked, colmax_enc,
                                                 wgt, assign, pos, count);
    scan_kernel<<<1, MS, 0, stream>>>(count, offset);
    fill_kernel<<<NQ / 256, 256, 0, stream>>>(assign, pos, offset, wgt,
                                              list, wsorted);
    update1_kernel<<<dim3(MS, USPLIT), DD, 0, stream>>>(value, wsorted, list,
                                                        offset, count, partial);
    update2_kernel<<<MS, DD, 0, stream>>>(partial, keys, out);
  } else {
    // --- fallback: round-1 verified fp32-VALU path ---
    size_t o2 = 0;
    auto alloc2 = [&](size_t bytes) -> void* {
      void* p = ws + o2;
      o2 += (bytes + 255) & ~(size_t)255;
      return p;
    };
    unsigned* colmax2 = (unsigned*)alloc2(MS * 4);
    int* count2  = (int*)alloc2(MS * 4);
    int* offset2 = (int*)alloc2(MS * 4);
    int* assign2 = (int*)alloc2((size_t)NQ * 4);
    float* sval2 = (float*)alloc2((size_t)NQ * 4);
    float* wgt2  = (float*)alloc2((size_t)NQ * 4);
    int* pos2    = (int*)alloc2((size_t)NQ * 4);
    int* list2   = (int*)alloc2((size_t)NQ * 4);
    float* wsorted2 = (float*)alloc2((size_t)NQ * 4);
    float* partial2 = (float*)alloc2((size_t)MS * USPLIT * DD * 4);

    hipMemsetAsync(colmax2, 0, MS * 4, stream);
    hipMemsetAsync(count2, 0, MS * 4, stream);

    score_kernel<<<NQ / BQ, 256, 0, stream>>>(query, keys, assign2, sval2, colmax2);
    weight_kernel<<<NQ / 256, 256, 0, stream>>>(sval2, assign2, colmax2, wgt2, pos2, count2);
    scan_kernel<<<1, MS, 0, stream>>>(count2, offset2);
    fill_kernel<<<NQ / 256, 256, 0, stream>>>(assign2, pos2, offset2, wgt2,
                                              list2, wsorted2);
    update1_kernel<<<dim3(MS, USPLIT), DD, 0, stream>>>(value, wsorted2, list2,
                                                        offset2, count2, partial2);
    update2_kernel<<<MS, DD, 0, stream>>>(partial2, keys, out);
  }
}

// Round 13
// 164.941 us; speedup vs baseline: 1.3474x; 1.0949x over previous
//
#include <hip/hip_runtime.h>
#include <hip/hip_bf16.h>
#include <cstdint>
#include <cstddef>

#define NQ 131072   // queries
#define MS 512      // memory slots
#define DD 256      // feature dim
#define USPLIT 16   // update-kernel per-slot parallel split
#define WTHR 1e-7f  // weight significance threshold (R12-verified: absmax unchanged)

typedef _Float16 f16;
typedef _Float16 f16x8 __attribute__((ext_vector_type(8)));
typedef float f32x4 __attribute__((ext_vector_type(4)));

// ---- monotone float <-> uint encoding for atomicMax on f32 ----
__device__ __forceinline__ unsigned enc_f32(float x) {
  unsigned u = __float_as_uint(x);
  return (u & 0x80000000u) ? ~u : (u | 0x80000000u);
}
__device__ __forceinline__ float dec_f32(unsigned u) {
  unsigned b = (u & 0x80000000u) ? (u & 0x7FFFFFFFu) : ~u;
  return __uint_as_float(b);
}

// exact 2-term f16 split of a float4
__device__ __forceinline__ void cvt4(const float4 v, uint2& uhi, uint2& ulo) {
  union U { f16 h[4]; uint2 u; } a, b;
  float x;
  x = v.x; a.h[0] = (f16)x; b.h[0] = (f16)(x - (float)a.h[0]);
  x = v.y; a.h[1] = (f16)x; b.h[1] = (f16)(x - (float)a.h[1]);
  x = v.z; a.h[2] = (f16)x; b.h[2] = (f16)(x - (float)a.h[2]);
  x = v.w; a.h[3] = (f16)x; b.h[3] = (f16)(x - (float)a.h[3]);
  uhi = a.u; ulo = b.u;
}

// Pre-split keys f32 -> f16 hi/lo:
//   byte offset = ((sch*8+kq)*4 + rg)*4096 + slot_in_half*16 + hf*8
__global__ __launch_bounds__(256) void ksplit_kernel(
    const float* __restrict__ keys, f16* __restrict__ kfh, f16* __restrict__ kfl)
{
  const int t = blockIdx.x * 256 + threadIdx.x;    // 0..32767
  const int S = t >> 6, c4 = t & 63;               // slot, float4-col
  const float4 v = *(const float4*)&keys[(size_t)S * DD + c4 * 4];
  const int sch = S >> 8, slot = S & 255;
  const int kq = c4 >> 3, rg = (c4 >> 1) & 3, hf = c4 & 1;
  uint2 uh, ul;
  cvt4(v, uh, ul);
  const size_t off = ((size_t)((sch * 8 + kq) * 4 + rg)) * 4096 + slot * 16 + hf * 8;
  *(uint2*)((char*)kfh + off) = uh;
  *(uint2*)((char*)kfl + off) = ul;
}

// ======================= score kernel (R11-verified, 151 us) =======================
// Block = 128 q x 128 s, 512 threads (8 waves: wq=wid>>2 in {0,1}, ws=wid&3).
// Wave tile 64x32 (acc[4][2] f32x4 = 32 regs). Register prefetch of next kq.
// (512,6): 3 blocks/CU co-resident -> cross-block pipe overlap (proven lever).
// LDS regions (2080 B = 128*16+32 pad):
//   KH @0, KL @8320, QH @16640, QL @24960 (end 33280)
//   reduction overlay: redRow u64[128][34] @0, redCol f32[128][2] @34816
#define R_KH 0
#define R_KL 8320
#define R_QH 16640
#define R_QL 24960
#define RSTR 2080

__global__ __launch_bounds__(512, 6) void score_mfma_kernel(
    const float* __restrict__ query,
    const f16* __restrict__ kfh, const f16* __restrict__ kfl,
    unsigned long long* __restrict__ rowPacked,
    unsigned* __restrict__ colmax_enc)
{
  __shared__ __align__(16) unsigned char LDS[36864];

  const int sc = blockIdx.x;      // slot quarter (0..3)
  const int qb = blockIdx.y;      // query block (0..1023)
  const int tid = threadIdx.x;
  const int l = tid & 63, wid = tid >> 6;
  const int wq = wid >> 2, ws = wid & 3;
  const int lg = l >> 4, ll = l & 15;
  const int q0 = qb * 128;

  f32x4 acc[4][2];
#pragma unroll
  for (int i = 0; i < 4; ++i)
#pragma unroll
    for (int j = 0; j < 2; ++j) acc[i][j] = (f32x4){0.f, 0.f, 0.f, 0.f};

  // K staging geometry: thread t stages slot kidx of region krg (16 B KH + KL)
  const int krg = tid >> 7, kidx = tid & 127;
  const size_t kbase0 = ((size_t)(((sc >> 1) * 8) * 4 + krg)) * 4096
                        + (sc & 1) * 2048 + kidx * 16;   // kq term added per iter
  // Q staging geometry: 2 float4 per thread
  const int qr0 = tid >> 3, qc0 = tid & 7;           // idx = tid
  const int qr1 = (tid + 512) >> 3;                  // idx = tid + 512 (same c4)
  const int qw0 = (qc0 >> 1) * RSTR + (qc0 & 1) * 8;

  uint4 kh_v, kl_v;
  float4 t4, t5;
  auto loadT = [&](int kq) {
    const size_t koff = kbase0 + (size_t)kq * 16384;   // (+kq*4)*4096
    kh_v = *(const uint4*)((const char*)kfh + koff);
    kl_v = *(const uint4*)((const char*)kfl + koff);
    const int kofs = kq * 32;
    t4 = *(const float4*)&query[(size_t)(q0 + qr0) * DD + kofs + qc0 * 4];
    t5 = *(const float4*)&query[(size_t)(q0 + qr1) * DD + kofs + qc0 * 4];
  };

  loadT(0);   // prologue
#pragma unroll
  for (int kq = 0; kq < 8; ++kq) {
    __syncthreads();   // prior compute done reading LDS
    // ---- consume prefetch: cvt + LDS writes ----
    {
      uint2 qh0, ql0, qh1, ql1;
      cvt4(t4, qh0, ql0);
      cvt4(t5, qh1, ql1);
      *(uint4*)&LDS[R_KH + krg * RSTR + kidx * 16] = kh_v;
      *(uint4*)&LDS[R_KL + krg * RSTR + kidx * 16] = kl_v;
      *(uint2*)&LDS[R_QH + qw0 + qr0 * 16] = qh0;
      *(uint2*)&LDS[R_QL + qw0 + qr0 * 16] = ql0;
      *(uint2*)&LDS[R_QH + qw0 + qr1 * 16] = qh1;
      *(uint2*)&LDS[R_QL + qw0 + qr1 * 16] = ql1;
    }
    __syncthreads();

    // ---- issue next-tile loads; latency hides under compute ----
    if (kq < 7) loadT(kq + 1);

    // ---- compute: B-frags resident (16 regs), A per-i (8 regs) ----
    f16x8 bh[2], bl[2];
#pragma unroll
    for (int j = 0; j < 2; ++j) {
      const int s = ws * 32 + j * 16 + ll;
      bh[j] = *(const f16x8*)&LDS[R_KH + lg * RSTR + s * 16];
      bl[j] = *(const f16x8*)&LDS[R_KL + lg * RSTR + s * 16];
    }
#pragma unroll
    for (int i = 0; i < 4; ++i) {
      const int r = wq * 64 + i * 16 + ll;
      const f16x8 ah = *(const f16x8*)&LDS[R_QH + lg * RSTR + r * 16];
      const f16x8 al = *(const f16x8*)&LDS[R_QL + lg * RSTR + r * 16];
#pragma unroll
      for (int j = 0; j < 2; ++j) {
        f32x4 c = acc[i][j];
        c = __builtin_amdgcn_mfma_f32_16x16x32_f16(ah, bl[j], c, 0, 0, 0);
        c = __builtin_amdgcn_mfma_f32_16x16x32_f16(al, bh[j], c, 0, 0, 0);
        c = __builtin_amdgcn_mfma_f32_16x16x32_f16(ah, bh[j], c, 0, 0, 0);
        acc[i][j] = c;
      }
    }
  }

  // ---- reductions. C layout (verified R3-R12): elem v of acc[i][j]:
  //   row = wq*64 + i*16 + lg*4 + v, col(block-local) = ws*32 + j*16 + ll
  __syncthreads();
  unsigned long long* redRow = (unsigned long long*)(LDS);   // [128][34]
  float* redCol = (float*)(LDS + 34816);                     // [128][2]

#pragma unroll
  for (int i = 0; i < 4; ++i)
#pragma unroll
    for (int v = 0; v < 4; ++v) {
      float bv = acc[i][0][v];
      int bc = ws * 32 + ll;
      {
        const float x = acc[i][1][v];
        const int c = ws * 32 + 16 + ll;
        if (x > bv) { bv = x; bc = c; }
      }
      const int gidx = sc * 128 + bc;
      unsigned long long p =
          ((unsigned long long)enc_f32(bv) << 32) | (unsigned)(~(unsigned)gidx);
      const unsigned long long q = __shfl_xor(p, 1);
      if (q > p) p = q;
      if ((ll & 1) == 0) {
        const int row = wq * 64 + i * 16 + lg * 4 + v;
        redRow[row * 34 + ws * 8 + (ll >> 1)] = p;
      }
    }

#pragma unroll
  for (int j = 0; j < 2; ++j) {
    float m = acc[0][j][0];
#pragma unroll
    for (int i = 0; i < 4; ++i)
#pragma unroll
      for (int v = 0; v < 4; ++v) m = fmaxf(m, acc[i][j][v]);
    m = fmaxf(m, __shfl_xor(m, 16));
    m = fmaxf(m, __shfl_xor(m, 32));
    if (l < 16) redCol[(ws * 32 + j * 16 + l) * 2 + wq] = m;
  }

  __syncthreads();
  if (tid < 128) {
    unsigned long long p = redRow[tid * 34];
#pragma unroll
    for (int w = 1; w < 32; ++w) {
      const unsigned long long q = redRow[tid * 34 + w];
      if (q > p) p = q;
    }
    atomicMax(&rowPacked[(size_t)qb * 128 + tid], p);
    const float v = fmaxf(redCol[tid * 2], redCol[tid * 2 + 1]);
    atomicMax(&colmax_enc[sc * 128 + tid], enc_f32(v));
  }
}

// ---- weights + per-slot counts; filter insignificant weights (R12-verified) ----
__global__ void weight2_kernel(const unsigned long long* __restrict__ rowPacked,
                               const unsigned* __restrict__ colmax_enc,
                               float* __restrict__ w, int* __restrict__ assign,
                               int* __restrict__ pos, int* __restrict__ count)
{
  const int i = blockIdx.x * blockDim.x + threadIdx.x;
  if (i >= NQ) return;
  const unsigned long long p = rowPacked[i];
  const int a = (int)(~(unsigned)(p & 0xFFFFFFFFull));
  const float sv = dec_f32((unsigned)(p >> 32));
  const float cm = dec_f32(colmax_enc[a]);
  const float wv = expf(sv - cm);
  w[i] = wv;
  assign[i] = a;
  pos[i] = (wv >= WTHR) ? atomicAdd(&count[a], 1) : -1;
}

// ======================= fallback path (round-1, verified) =======================
#define BQ 128
#define BM 128
#define DC 32
#define PAD 132

__global__ __launch_bounds__(256) void score_kernel(
    const float* __restrict__ query, const float* __restrict__ keys,
    int* __restrict__ assign_out, float* __restrict__ sval_out,
    unsigned* __restrict__ colmax_enc)
{
  __shared__ float Qs[DC][PAD];
  __shared__ float Ks[DC][PAD];
  __shared__ float redV[BQ * 16];
  __shared__ int   redI[BQ * 16];

  const int tid = threadIdx.x;
  const int ty = tid >> 4;
  const int tx = tid & 15;
  const int q0 = blockIdx.x * BQ;

  float bestV = -3.4e38f;
  int   bestI = 0;

  for (int mc = 0; mc < MS / BM; ++mc) {
    float acc[8][8];
#pragma unroll
    for (int i = 0; i < 8; ++i)
#pragma unroll
      for (int j = 0; j < 8; ++j) acc[i][j] = 0.f;

    for (int dc = 0; dc < DD; dc += DC) {
      __syncthreads();
#pragma unroll
      for (int it = 0; it < 4; ++it) {
        const int r = (tid >> 3) + it * 32;
        const int d = (tid & 7) * 4;
        const float4 qv = *reinterpret_cast<const float4*>(
            &query[(size_t)(q0 + r) * DD + dc + d]);
        Qs[d + 0][r] = qv.x; Qs[d + 1][r] = qv.y;
        Qs[d + 2][r] = qv.z; Qs[d + 3][r] = qv.w;
        const float4 kv = *reinterpret_cast<const float4*>(
            &keys[(size_t)(mc * BM + r) * DD + dc + d]);
        Ks[d + 0][r] = kv.x; Ks[d + 1][r] = kv.y;
        Ks[d + 2][r] = kv.z; Ks[d + 3][r] = kv.w;
      }
      __syncthreads();
#pragma unroll
      for (int d = 0; d < DC; ++d) {
        float a[8], b[8];
        *reinterpret_cast<float4*>(&a[0]) = *reinterpret_cast<const float4*>(&Qs[d][ty * 8]);
        *reinterpret_cast<float4*>(&a[4]) = *reinterpret_cast<const float4*>(&Qs[d][ty * 8 + 4]);
        *reinterpret_cast<float4*>(&b[0]) = *reinterpret_cast<const float4*>(&Ks[d][tx * 8]);
        *reinterpret_cast<float4*>(&b[4]) = *reinterpret_cast<const float4*>(&Ks[d][tx * 8 + 4]);
#pragma unroll
        for (int i = 0; i < 8; ++i)
#pragma unroll
          for (int j = 0; j < 8; ++j)
            acc[i][j] = fmaf(a[i], b[j], acc[i][j]);
      }
    }

    __syncthreads();
#pragma unroll
    for (int i = 0; i < 8; ++i) {
      float v = acc[i][0]; int jj = 0;
#pragma unroll
      for (int j = 1; j < 8; ++j)
        if (acc[i][j] > v) { v = acc[i][j]; jj = j; }
      redV[(ty * 8 + i) * 16 + tx] = v;
      redI[(ty * 8 + i) * 16 + tx] = mc * BM + tx * 8 + jj;
    }
    __syncthreads();
    if (tid < BQ) {
#pragma unroll
      for (int t = 0; t < 16; ++t) {
        float v = redV[tid * 16 + t];
        if (v > bestV) { bestV = v; bestI = redI[tid * 16 + t]; }
      }
    }
    __syncthreads();
#pragma unroll
    for (int j = 0; j < 8; ++j) {
      float v = acc[0][j];
#pragma unroll
      for (int i = 1; i < 8; ++i) v = fmaxf(v, acc[i][j]);
      redV[(tx * 8 + j) * 16 + ty] = v;
    }
    __syncthreads();
    if (tid < BM) {
      float v = redV[tid * 16];
#pragma unroll
      for (int t = 1; t < 16; ++t) v = fmaxf(v, redV[tid * 16 + t]);
      atomicMax(&colmax_enc[mc * BM + tid], enc_f32(v));
    }
  }

  if (tid < BQ) {
    assign_out[q0 + tid] = bestI;
    sval_out[q0 + tid]   = bestV;
  }
}

__global__ void weight_kernel(const float* __restrict__ sval,
                              const int* __restrict__ assign,
                              const unsigned* __restrict__ colmax_enc,
                              float* __restrict__ w,
                              int* __restrict__ pos,
                              int* __restrict__ count)
{
  int i = blockIdx.x * blockDim.x + threadIdx.x;
  if (i >= NQ) return;
  int a = assign[i];
  float cm = dec_f32(colmax_enc[a]);
  const float wv = expf(sval[i] - cm);
  w[i] = wv;
  pos[i] = (wv >= WTHR) ? atomicAdd(&count[a], 1) : -1;
}

// ======================= shared tail kernels =======================

__global__ void scan_kernel(const int* __restrict__ count, int* __restrict__ offset)
{
  __shared__ int s[MS];
  int t = threadIdx.x;
  int c = count[t];
  s[t] = c;
  __syncthreads();
  for (int off = 1; off < MS; off <<= 1) {
    int v = (t >= off) ? s[t - off] : 0;
    __syncthreads();
    s[t] += v;
    __syncthreads();
  }
  offset[t] = s[t] - c;
}

// CSR fill (filtered); also writes CSR-ordered weights
__global__ void fill_kernel(const int* __restrict__ assign,
                            const int* __restrict__ pos,
                            const int* __restrict__ offset,
                            const float* __restrict__ w,
                            int* __restrict__ list,
                            float* __restrict__ wsorted)
{
  int i = blockIdx.x * blockDim.x + threadIdx.x;
  if (i >= NQ) return;
  const int ps = pos[i];
  if (ps < 0) return;                 // filtered: weight below WTHR
  int a = assign[i];
  const int p = offset[a] + ps;
  list[p] = i;
  wsorted[p] = w[i];
}

// stage 1: per-(slot, chunk) partial weighted sum
__global__ __launch_bounds__(256) void update1_kernel(
    const float* __restrict__ value, const float* __restrict__ wsorted,
    const int* __restrict__ list, const int* __restrict__ offset,
    const int* __restrict__ count, float* __restrict__ partial)
{
  const int m = blockIdx.x, c = blockIdx.y, d = threadIdx.x;
  const int off = offset[m];
  const int cnt = count[m];
  float acc = 0.f;
  int j = c;
  for (; j + USPLIT < cnt; j += 2 * USPLIT) {
    const int i0 = list[off + j];
    const int i1 = list[off + j + USPLIT];
    const float w0 = wsorted[off + j], w1 = wsorted[off + j + USPLIT];
    const float v0 = value[(size_t)i0 * DD + d];
    const float v1 = value[(size_t)i1 * DD + d];
    acc = fmaf(w0, v0, acc);
    acc = fmaf(w1, v1, acc);
  }
  if (j < cnt) {
    const int i = list[off + j];
    acc = fmaf(wsorted[off + j], value[(size_t)i * DD + d], acc);
  }
  partial[((size_t)m * USPLIT + c) * DD + d] = acc;
}

// stage 2: sum partials + keys, L2-normalize, store
__global__ __launch_bounds__(256) void update2_kernel(
    const float* __restrict__ partial, const float* __restrict__ keys,
    float* __restrict__ out)
{
  const int m = blockIdx.x, d = threadIdx.x;
  float x = keys[(size_t)m * DD + d];
#pragma unroll
  for (int c = 0; c < USPLIT; ++c)
    x += partial[((size_t)m * USPLIT + c) * DD + d];
  float ss = x * x;
#pragma unroll
  for (int o = 1; o < 64; o <<= 1) ss += __shfl_xor(ss, o);
  __shared__ float wsum[4];
  if ((threadIdx.x & 63) == 0) wsum[threadIdx.x >> 6] = ss;
  __syncthreads();
  float tot = wsum[0] + wsum[1] + wsum[2] + wsum[3];
  float den = fmaxf(sqrtf(tot), 1e-12f);
  out[(size_t)m * DD + d] = x / den;
}

// ======================= launcher =======================

extern "C" void kernel_launch(void* const* d_in, const int* in_sizes, int n_in,
                              void* d_out, int out_size, void* d_ws, size_t ws_size,
                              hipStream_t stream)
{
  const float* keys  = (const float*)d_in[0];
  const float* query = (const float*)d_in[1];
  const float* value = (const float*)d_in[2];
  float* out = (float*)d_out;

  char* ws = (char*)d_ws;
  size_t o = 0;
  auto alloc = [&](size_t bytes) -> void* {
    void* p = ws + o;
    o += (bytes + 255) & ~(size_t)255;
    return p;
  };

  f16* kfh = (f16*)alloc((size_t)MS * DD * 2);
  f16* kfl = (f16*)alloc((size_t)MS * DD * 2);
  unsigned long long* rowPacked = (unsigned long long*)alloc((size_t)NQ * 8);
  unsigned* colmax_enc = (unsigned*)alloc(MS * 4);
  int* count  = (int*)alloc(MS * 4);
  int* offset = (int*)alloc(MS * 4);
  int* assign = (int*)alloc((size_t)NQ * 4);
  float* wgt  = (float*)alloc((size_t)NQ * 4);
  int* pos    = (int*)alloc((size_t)NQ * 4);
  int* list   = (int*)alloc((size_t)NQ * 4);
  float* wsorted = (float*)alloc((size_t)NQ * 4);
  float* partial = (float*)alloc((size_t)MS * USPLIT * DD * 4);
  const size_t mfma_need = o;

  if (ws_size >= mfma_need) {
    hipMemsetAsync(rowPacked, 0, (size_t)NQ * 8, stream);
    hipMemsetAsync(colmax_enc, 0, MS * 4, stream);
    hipMemsetAsync(count, 0, MS * 4, stream);

    ksplit_kernel<<<128, 256, 0, stream>>>(keys, kfh, kfl);
    score_mfma_kernel<<<dim3(4, 1024), 512, 0, stream>>>(query, kfh, kfl,
                                                         rowPacked, colmax_enc);
    weight2_kernel<<<NQ / 256, 256, 0, stream>>>(rowPacked, colmax_enc,
                                                 wgt, assign, pos, count);
    scan_kernel<<<1, MS, 0, stream>>>(count, offset);
    fill_kernel<<<NQ / 256, 256, 0, stream>>>(assign, pos, offset, wgt,
                                              list, wsorted);
    update1_kernel<<<dim3(MS, USPLIT), DD, 0, stream>>>(value, wsorted, list,
                                                        offset, count, partial);
    update2_kernel<<<MS, DD, 0, stream>>>(partial, keys, out);
  } else {
    // --- fallback: round-1 verified fp32-VALU path ---
    size_t o2 = 0;
    auto alloc2 = [&](size_t bytes) -> void* {
      void* p = ws + o2;
      o2 += (bytes + 255) & ~(size_t)255;
      return p;
    };
    unsigned* colmax2 = (unsigned*)alloc2(MS * 4);
    int* count2  = (int*)alloc2(MS * 4);
    int* offset2 = (int*)alloc2(MS * 4);
    int* assign2 = (int*)alloc2((size_t)NQ * 4);
    float* sval2 = (float*)alloc2((size_t)NQ * 4);
    float* wgt2  = (float*)alloc2((size_t)NQ * 4);
    int* pos2    = (int*)alloc2((size_t)NQ * 4);
    int* list2   = (int*)alloc2((size_t)NQ * 4);
    float* wsorted2 = (float*)alloc2((size_t)NQ * 4);
    float* partial2 = (float*)alloc2((size_t)MS * USPLIT * DD * 4);

    hipMemsetAsync(colmax2, 0, MS * 4, stream);
    hipMemsetAsync(count2, 0, MS * 4, stream);

    score_kernel<<<NQ / BQ, 256, 0, stream>>>(query, keys, assign2, sval2, colmax2);
    weight_kernel<<<NQ / 256, 256, 0, stream>>>(sval2, assign2, colmax2, wgt2, pos2, count2);
    scan_kernel<<<1, MS, 0, stream>>>(count2, offset2);
    fill_kernel<<<NQ / 256, 256, 0, stream>>>(assign2, pos2, offset2, wgt2,
                                              list2, wsorted2);
    update1_kernel<<<dim3(MS, USPLIT), DD, 0, stream>>>(value, wsorted2, list2,
                                                        offset2, count2, partial2);
    update2_kernel<<<MS, DD, 0, stream>>>(partial2, keys, out);
  }
}